// Round 11
// baseline (420.667 us; speedup 1.0000x reference)
//
#include <hip/hip_runtime.h>

#define BLOCK 256
#define NW (BLOCK / 64)
#define GRID_MAX 2048

// u-space bin thresholds: L[k] = logit(E_k) where E_k is the EXACT float
// value of k/10 (computed in double).  g = sigmoid(u) >= E_k  <=>  u >= L[k].
// (u = (1-2t)*x via sign-bit xor; t in {0,1} exactly.)
__device__ __forceinline__ void process_u(float u, float a[10], unsigned G[10]) {
    const float L[10] = {0.0f,
        -2.1972245607794f, -1.3862943424934f, -0.8472978036209f,
        -0.4054650832729f,  0.0f,              0.4054652074492f,
         0.8472978036209f,  1.3862944356257f,  2.1972243124267f};
    // bce = softplus(u) = max(u,0) + ln2*log2(1+exp(-|u|))
    float e   = __expf(-fabsf(u));     // v_mul(log2e, -|u|) + v_exp
    float ope = 1.0f + e;
    float bce = fmaxf(u, 0.0f) + 0.693147180559945f * __log2f(ope);
    a[0] += bce;                       // total bce sum
#pragma unroll
    for (int k = 1; k <= 9; ++k) {
        bool m = (u >= L[k]);
        a[k] += m ? bce : 0.0f;                       // A[k] = sum bce [u>=L]
        G[k] += (unsigned)__popcll(__ballot(m));      // wave-count, SALU path
    }
}

__device__ __forceinline__ float make_u(float x, float tv) {
    return __uint_as_float(__float_as_uint(x) ^ (__float_as_uint(tv) << 8));
}

#define PROC8(P0, P1, T0, T1)                       \
    do {                                            \
        process_u(make_u((P0).x, (T0).x), a, G);    \
        process_u(make_u((P0).y, (T0).y), a, G);    \
        process_u(make_u((P0).z, (T0).z), a, G);    \
        process_u(make_u((P0).w, (T0).w), a, G);    \
        process_u(make_u((P1).x, (T1).x), a, G);    \
        process_u(make_u((P1).y, (T1).y), a, G);    \
        process_u(make_u((P1).z, (T1).z), a, G);    \
        process_u(make_u((P1).w, (T1).w), a, G);    \
    } while (0)

// direct==0: per-block partials {G[10], A[10]} to ws.
// direct==1: single block computes final loss (ws-less fallback).
__global__ __launch_bounds__(BLOCK) void ghmc_main(
    const float* __restrict__ pred, const float* __restrict__ target,
    unsigned int* __restrict__ ws_cnt, float* __restrict__ ws_sum,
    long long nvec8, long long ntot, int direct, float* __restrict__ out) {
    float    a[10];
    unsigned G[10];
#pragma unroll
    for (int k = 0; k < 10; ++k) { a[k] = 0.0f; G[k] = 0u; }

    const long long stride = (long long)gridDim.x * BLOCK;
    const long long tid0   = (long long)blockIdx.x * BLOCK + threadIdx.x;

    // main domain rounded DOWN to a wave multiple so every wave iteration is
    // fully convergent (ballot uniformity); residual done by block 0 below.
    // All loop conditions below are wave-uniform: nvec8f is 64-aligned and
    // i = base + lane with base a multiple of 64.
    const long long nvec8f = nvec8 & ~63LL;
    const float4* p4 = (const float4*)pred;
    const float4* t4 = (const float4*)target;

    // Software-pipelined grid-stride loop: issue iteration i+1's four
    // float4 loads BEFORE processing iteration i, so the ~600-cycle memory
    // latency hides under the ~450-cycle compute of the current iteration.
    // (R4 kernel had VGPR=32 -> no prefetch -> lockstep stalls, VALUBusy 35%.)
    {
        long long i = tid0;
        if (i < nvec8f) {
            float4 cp0 = p4[2 * i], cp1 = p4[2 * i + 1];
            float4 ct0 = t4[2 * i], ct1 = t4[2 * i + 1];
            long long nx = i + stride;
            while (nx < nvec8f) {
                float4 np0 = p4[2 * nx], np1 = p4[2 * nx + 1];
                float4 nt0 = t4[2 * nx], nt1 = t4[2 * nx + 1];
                PROC8(cp0, cp1, ct0, ct1);
                cp0 = np0; cp1 = np1; ct0 = nt0; ct1 = nt1;
                nx += stride;
            }
            PROC8(cp0, cp1, ct0, ct1);
        }
    }

    // residual: elements [nvec8f*8, ntot), < 64*8+8 = 520 elems.
    // Block 0 only, full-wave predicated (invalid lanes: u=-1e30 -> m=false,
    // bce = max(-1e30,0) + ln2*log2(1+exp(-inf)) = 0).
    if (blockIdx.x == 0) {
        long long base = nvec8f << 3;
        long long rem  = ntot - base;
        int niter = (int)((rem + BLOCK - 1) / BLOCK);   // block-uniform
        for (int it = 0; it < niter; ++it) {
            long long p = base + (long long)it * BLOCK + threadIdx.x;
            bool v = (p < ntot);
            long long pc = v ? p : 0;
            float x  = pred[pc];
            float tv = target[pc];
            float u  = v ? make_u(x, tv) : -1e30f;
            process_u(u, a, G);
        }
    }

    // wave reduction for float sums (G already wave-uniform via ballot)
#pragma unroll
    for (int k = 0; k < 10; ++k) {
        float s = a[k];
#pragma unroll
        for (int off = 32; off > 0; off >>= 1) s += __shfl_down(s, off, 64);
        a[k] = s;
    }

    __shared__ unsigned sG[NW][10];
    __shared__ float    sA[NW][10];
    int lane = threadIdx.x & 63;
    int wid  = threadIdx.x >> 6;
    if (lane == 0) {
#pragma unroll
        for (int k = 0; k < 10; ++k) { sG[wid][k] = G[k]; sA[wid][k] = a[k]; }
    }
    __syncthreads();
    if (threadIdx.x == 0) {
        unsigned gg[10];
        float    aa[10];
#pragma unroll
        for (int k = 0; k < 10; ++k) {
            unsigned c = 0; float s = 0.0f;
#pragma unroll
            for (int w = 0; w < NW; ++w) { c += sG[w][k]; s += sA[w][k]; }
            gg[k] = c; aa[k] = s;
        }
        if (direct) {
            // single block: gg/aa are the global totals
            double loss = 0.0;
#pragma unroll
            for (int j = 0; j < 10; ++j) {
                long long n = (j == 0) ? (long long)ntot - (long long)gg[1]
                            : (j == 9) ? (long long)gg[9]
                                       : (long long)gg[j] - (long long)gg[j + 1];
                double S = (j == 0) ? (double)aa[0] - (double)aa[1]
                         : (j == 9) ? (double)aa[9]
                                    : (double)aa[j] - (double)aa[j + 1];
                loss += S / (double)(n > 0 ? n : 1);
            }
            out[0] = (float)(0.075 * loss);   // GHM/10; `total` cancels
        } else {
#pragma unroll
            for (int k = 0; k < 10; ++k) {
                ws_cnt[(long long)blockIdx.x * 10 + k] = gg[k];
                ws_sum[(long long)blockIdx.x * 10 + k] = aa[k];
            }
        }
    }
}

// Deterministic finalize: 1 block sums per-block partials, telescopes,
// computes loss in double.
__global__ __launch_bounds__(256) void ghmc_final(
    const unsigned int* __restrict__ ws_cnt, const float* __restrict__ ws_sum,
    int nblocks, long long ntot, float* __restrict__ out) {
    unsigned long long c[10] = {};
    double             s[10] = {};
    for (int b = threadIdx.x; b < nblocks; b += 256) {
#pragma unroll
        for (int k = 0; k < 10; ++k) {
            c[k] += ws_cnt[b * 10 + k];
            s[k] += (double)ws_sum[b * 10 + k];
        }
    }
#pragma unroll
    for (int k = 0; k < 10; ++k) {
        unsigned long long cc = c[k];
        double             ss = s[k];
#pragma unroll
        for (int off = 32; off > 0; off >>= 1) {
            cc += __shfl_down(cc, off, 64);
            ss += __shfl_down(ss, off, 64);
        }
        c[k] = cc;
        s[k] = ss;
    }
    __shared__ unsigned long long sc[4][10];
    __shared__ double             sd[4][10];
    int lane = threadIdx.x & 63;
    int wid  = threadIdx.x >> 6;
    if (lane == 0) {
#pragma unroll
        for (int k = 0; k < 10; ++k) { sc[wid][k] = c[k]; sd[wid][k] = s[k]; }
    }
    __syncthreads();
    if (threadIdx.x == 0) {
        unsigned long long gg[11];
        double             aa[11];
#pragma unroll
        for (int k = 0; k < 10; ++k) {
            unsigned long long cc = 0; double ss = 0.0;
#pragma unroll
            for (int w = 0; w < 4; ++w) { cc += sc[w][k]; ss += sd[w][k]; }
            gg[k] = cc; aa[k] = ss;
        }
        gg[10] = 0ull; aa[10] = 0.0;
        gg[0]  = (unsigned long long)ntot;   // G[0] == total element count
        double loss = 0.0;
#pragma unroll
        for (int j = 0; j < 10; ++j) {
            long long n = (long long)gg[j] - (long long)gg[j + 1];
            double    S = aa[j] - aa[j + 1];
            loss += S / (double)(n > 0 ? n : 1);
        }
        out[0] = (float)(0.075 * loss);   // GHM/10; `total` cancels
    }
}

extern "C" void kernel_launch(void* const* d_in, const int* in_sizes, int n_in,
                              void* d_out, int out_size, void* d_ws, size_t ws_size,
                              hipStream_t stream) {
    const float* pred   = (const float*)d_in[0];
    const float* target = (const float*)d_in[1];
    float*       out    = (float*)d_out;
    long long n     = (long long)in_sizes[0];
    long long nvec8 = n >> 3;

    // per-block partials: 10 uint + 10 float = 80 B
    const size_t per_block = 10 * (sizeof(unsigned int) + sizeof(float));
    long long g = (nvec8 + BLOCK - 1) / BLOCK;
    if (g > GRID_MAX) g = GRID_MAX;
    long long g_ws = (long long)(ws_size / per_block);
    if (g > g_ws) g = g_ws;

    if (g < 1) {
        // ws-less fallback: one block does everything (slow but correct)
        ghmc_main<<<1, BLOCK, 0, stream>>>(pred, target, nullptr, nullptr,
                                           nvec8, n, 1, out);
        return;
    }

    unsigned int* ws_cnt = (unsigned int*)d_ws;
    float*        ws_sum = (float*)((char*)d_ws + (size_t)g * 10 * sizeof(unsigned int));

    ghmc_main<<<(int)g, BLOCK, 0, stream>>>(pred, target, ws_cnt, ws_sum,
                                            nvec8, n, 0, out);
    ghmc_final<<<1, 256, 0, stream>>>(ws_cnt, ws_sum, (int)g, n, out);
}

// Round 13
// 415.100 us; speedup vs baseline: 1.0134x; 1.0134x over previous
//
#include <hip/hip_runtime.h>

#define BLOCK 256
#define NW (BLOCK / 64)
#define GRID_MAX 2048

// u-space bin thresholds: L[k] = logit(E_k) where E_k is the EXACT float
// value of k/10 (computed in double).  g = sigmoid(u) >= E_k  <=>  u >= L[k].
// (u = (1-2t)*x via sign-bit xor; t in {0,1} exactly.)
__device__ __forceinline__ void process_u(float u, float a[10], unsigned G[10]) {
    const float L[10] = {0.0f,
        -2.1972245607794f, -1.3862943424934f, -0.8472978036209f,
        -0.4054650832729f,  0.0f,              0.4054652074492f,
         0.8472978036209f,  1.3862944356257f,  2.1972243124267f};
    // bce = softplus(u) = max(u,0) + ln2*log2(1+exp(-|u|))
    float e   = __expf(-fabsf(u));     // v_mul(log2e, -|u|) + v_exp
    float ope = 1.0f + e;
    float bce = fmaxf(u, 0.0f) + 0.693147180559945f * __log2f(ope);
    a[0] += bce;                       // total bce sum
#pragma unroll
    for (int k = 1; k <= 9; ++k) {
        bool m = (u >= L[k]);
        a[k] += m ? bce : 0.0f;                       // A[k] = sum bce [u>=L]
        G[k] += (unsigned)__popcll(__ballot(m));      // wave-count, SALU path
    }
}

__device__ __forceinline__ float make_u(float x, float tv) {
    return __uint_as_float(__float_as_uint(x) ^ (__float_as_uint(tv) << 8));
}

#define PROC4(P, T)                               \
    do {                                          \
        process_u(make_u((P).x, (T).x), a, G);    \
        process_u(make_u((P).y, (T).y), a, G);    \
        process_u(make_u((P).z, (T).z), a, G);    \
        process_u(make_u((P).w, (T).w), a, G);    \
    } while (0)

// direct==0: per-block partials {G[10], A[10]} to ws.
// direct==1: single block computes final loss (ws-less fallback).
__global__ __launch_bounds__(BLOCK) void ghmc_main(
    const float* __restrict__ pred, const float* __restrict__ target,
    unsigned int* __restrict__ ws_cnt, float* __restrict__ ws_sum,
    long long nvec4, long long ntot, int direct, float* __restrict__ out) {
    float    a[10];
    unsigned G[10];
#pragma unroll
    for (int k = 0; k < 10; ++k) { a[k] = 0.0f; G[k] = 0u; }

    const long long stride = (long long)gridDim.x * BLOCK;
    const long long tid0   = (long long)blockIdx.x * BLOCK + threadIdx.x;

    // main domain rounded DOWN to a wave multiple so every wave iteration is
    // fully convergent (ballot uniformity); residual done by block 0 below.
    // All loop conditions are wave-uniform: nvec4f is 64-aligned and lanes of
    // a wave hold consecutive indices.
    const long long nvec4f = nvec4 & ~63LL;
    const float4* p4 = (const float4*)pred;
    const float4* t4 = (const float4*)target;

    // Software-pipelined grid-stride loop over 4-elem chunks.
    // R11 post-mortem: the compiler SANK the prefetch loads back to their
    // use point (VGPR stayed 32 -> pipeline destroyed).  The fix is
    // __builtin_amdgcn_sched_barrier(0) right after the prefetch issue:
    // the machine scheduler cannot move the loads across it, so the
    // global_load_dwordx4 pair for chunk i+stride stays ABOVE the compute
    // of chunk i, and its s_waitcnt lands after.  4-elem chunks (8 data
    // VGPRs in flight) keep peak pressure < 64 VGPR (occupancy cliff, m69).
    {
        long long i = tid0;
        if (i < nvec4f) {
            float4 cp = p4[i];
            float4 ct = t4[i];
            long long nx = i + stride;
            while (nx < nvec4f) {
                float4 np = p4[nx];
                float4 nt = t4[nx];
                __builtin_amdgcn_sched_barrier(0);   // pin loads above compute
                PROC4(cp, ct);
                cp = np; ct = nt;
                nx += stride;
            }
            PROC4(cp, ct);
        }
    }

    // residual: elements [nvec4f*4, ntot), < 64*4+4 = 260 elems.
    // Block 0 only, full-wave predicated (invalid lanes: u=-1e30 -> m=false,
    // bce = max(-1e30,0) + ln2*log2(1+exp(-inf)) = 0).
    if (blockIdx.x == 0) {
        long long base = nvec4f << 2;
        long long rem  = ntot - base;
        int niter = (int)((rem + BLOCK - 1) / BLOCK);   // block-uniform
        for (int it = 0; it < niter; ++it) {
            long long p = base + (long long)it * BLOCK + threadIdx.x;
            bool v = (p < ntot);
            long long pc = v ? p : 0;
            float x  = pred[pc];
            float tv = target[pc];
            float u  = v ? make_u(x, tv) : -1e30f;
            process_u(u, a, G);
        }
    }

    // wave reduction for float sums (G already wave-uniform via ballot)
#pragma unroll
    for (int k = 0; k < 10; ++k) {
        float s = a[k];
#pragma unroll
        for (int off = 32; off > 0; off >>= 1) s += __shfl_down(s, off, 64);
        a[k] = s;
    }

    __shared__ unsigned sG[NW][10];
    __shared__ float    sA[NW][10];
    int lane = threadIdx.x & 63;
    int wid  = threadIdx.x >> 6;
    if (lane == 0) {
#pragma unroll
        for (int k = 0; k < 10; ++k) { sG[wid][k] = G[k]; sA[wid][k] = a[k]; }
    }
    __syncthreads();
    if (threadIdx.x == 0) {
        unsigned gg[10];
        float    aa[10];
#pragma unroll
        for (int k = 0; k < 10; ++k) {
            unsigned c = 0; float s = 0.0f;
#pragma unroll
            for (int w = 0; w < NW; ++w) { c += sG[w][k]; s += sA[w][k]; }
            gg[k] = c; aa[k] = s;
        }
        if (direct) {
            // single block: gg/aa are the global totals
            double loss = 0.0;
#pragma unroll
            for (int j = 0; j < 10; ++j) {
                long long n = (j == 0) ? (long long)ntot - (long long)gg[1]
                            : (j == 9) ? (long long)gg[9]
                                       : (long long)gg[j] - (long long)gg[j + 1];
                double S = (j == 0) ? (double)aa[0] - (double)aa[1]
                         : (j == 9) ? (double)aa[9]
                                    : (double)aa[j] - (double)aa[j + 1];
                loss += S / (double)(n > 0 ? n : 1);
            }
            out[0] = (float)(0.075 * loss);   // GHM/10; `total` cancels
        } else {
#pragma unroll
            for (int k = 0; k < 10; ++k) {
                ws_cnt[(long long)blockIdx.x * 10 + k] = gg[k];
                ws_sum[(long long)blockIdx.x * 10 + k] = aa[k];
            }
        }
    }
}

// Deterministic finalize: 1 block sums per-block partials, telescopes,
// computes loss in double.
__global__ __launch_bounds__(256) void ghmc_final(
    const unsigned int* __restrict__ ws_cnt, const float* __restrict__ ws_sum,
    int nblocks, long long ntot, float* __restrict__ out) {
    unsigned long long c[10] = {};
    double             s[10] = {};
    for (int b = threadIdx.x; b < nblocks; b += 256) {
#pragma unroll
        for (int k = 0; k < 10; ++k) {
            c[k] += ws_cnt[b * 10 + k];
            s[k] += (double)ws_sum[b * 10 + k];
        }
    }
#pragma unroll
    for (int k = 0; k < 10; ++k) {
        unsigned long long cc = c[k];
        double             ss = s[k];
#pragma unroll
        for (int off = 32; off > 0; off >>= 1) {
            cc += __shfl_down(cc, off, 64);
            ss += __shfl_down(ss, off, 64);
        }
        c[k] = cc;
        s[k] = ss;
    }
    __shared__ unsigned long long sc[4][10];
    __shared__ double             sd[4][10];
    int lane = threadIdx.x & 63;
    int wid  = threadIdx.x >> 6;
    if (lane == 0) {
#pragma unroll
        for (int k = 0; k < 10; ++k) { sc[wid][k] = c[k]; sd[wid][k] = s[k]; }
    }
    __syncthreads();
    if (threadIdx.x == 0) {
        unsigned long long gg[11];
        double             aa[11];
#pragma unroll
        for (int k = 0; k < 10; ++k) {
            unsigned long long cc = 0; double ss = 0.0;
#pragma unroll
            for (int w = 0; w < 4; ++w) { cc += sc[w][k]; ss += sd[w][k]; }
            gg[k] = cc; aa[k] = ss;
        }
        gg[10] = 0ull; aa[10] = 0.0;
        gg[0]  = (unsigned long long)ntot;   // G[0] == total element count
        double loss = 0.0;
#pragma unroll
        for (int j = 0; j < 10; ++j) {
            long long n = (long long)gg[j] - (long long)gg[j + 1];
            double    S = aa[j] - aa[j + 1];
            loss += S / (double)(n > 0 ? n : 1);
        }
        out[0] = (float)(0.075 * loss);   // GHM/10; `total` cancels
    }
}

extern "C" void kernel_launch(void* const* d_in, const int* in_sizes, int n_in,
                              void* d_out, int out_size, void* d_ws, size_t ws_size,
                              hipStream_t stream) {
    const float* pred   = (const float*)d_in[0];
    const float* target = (const float*)d_in[1];
    float*       out    = (float*)d_out;
    long long n     = (long long)in_sizes[0];
    long long nvec4 = n >> 2;

    // per-block partials: 10 uint + 10 float = 80 B
    const size_t per_block = 10 * (sizeof(unsigned int) + sizeof(float));
    long long g = (nvec4 + BLOCK - 1) / BLOCK;
    if (g > GRID_MAX) g = GRID_MAX;
    long long g_ws = (long long)(ws_size / per_block);
    if (g > g_ws) g = g_ws;

    if (g < 1) {
        // ws-less fallback: one block does everything (slow but correct)
        ghmc_main<<<1, BLOCK, 0, stream>>>(pred, target, nullptr, nullptr,
                                           nvec4, n, 1, out);
        return;
    }

    unsigned int* ws_cnt = (unsigned int*)d_ws;
    float*        ws_sum = (float*)((char*)d_ws + (size_t)g * 10 * sizeof(unsigned int));

    ghmc_main<<<(int)g, BLOCK, 0, stream>>>(pred, target, ws_cnt, ws_sum,
                                            nvec4, n, 0, out);
    ghmc_final<<<1, 256, 0, stream>>>(ws_cnt, ws_sum, (int)g, n, out);
}